// Round 3
// baseline (512.137 us; speedup 1.0000x reference)
//
#include <hip/hip_runtime.h>

#define B_  2
#define S_  2048
#define D_  1024
#define H_  16
#define DH_ 64

typedef _Float16 f16;
typedef f16   f16x2 __attribute__((ext_vector_type(2)));
typedef f16   f16x4 __attribute__((ext_vector_type(4)));
typedef f16   f16x8 __attribute__((ext_vector_type(8)));
typedef float f32x4 __attribute__((ext_vector_type(4)));
typedef float f32x16 __attribute__((ext_vector_type(16)));

static __device__ __forceinline__ f16x8 ldsm8(const f16* p) {
    return *reinterpret_cast<const f16x8*>(p);
}

// C[M,N] = A[M,K] @ W[N,K]^T (+bias)*scale.  M=4096, N=K=1024.
// OUT: 0 = f32 row-major, 1 = f16 row-major, 2 = f16 transposed-per-head
//      (vtg[((b*16+h)*64+d)*2048 + s] = C[b*2048+s][h*64+d])
template<int A_IS_F16, int OUT>
__global__ __launch_bounds__(256)
void gemm_bt(const void* __restrict__ Ap, const float* __restrict__ W,
             const float* __restrict__ bias, void* __restrict__ Cp, float scale)
{
    constexpr int K = 1024, N = 1024;
    __shared__ __align__(16) f16 As[128][40];
    __shared__ __align__(16) f16 Bs[128][40];
    const int t  = threadIdx.x;
    const int bm = blockIdx.y * 128;
    const int bn = blockIdx.x * 128;
    const int w  = t >> 6, l = t & 63;
    const int wr = w >> 1, wc = w & 1;
    const int lr = l & 15, lg = l >> 4;

    f32x4 acc[4][4];
    #pragma unroll
    for (int m = 0; m < 4; ++m)
        #pragma unroll
        for (int n = 0; n < 4; ++n)
            acc[m][n] = (f32x4){0.f, 0.f, 0.f, 0.f};

    for (int kt = 0; kt < K / 32; ++kt) {
        if (A_IS_F16) {
            const f16* A = (const f16*)Ap;
            #pragma unroll
            for (int i = 0; i < 2; ++i) {
                int idx = t + i * 256;
                int row = idx >> 2, g = idx & 3;
                *reinterpret_cast<uint4*>(&As[row][g * 8]) =
                    *reinterpret_cast<const uint4*>(A + (size_t)(bm + row) * K + kt * 32 + g * 8);
            }
        } else {
            const float* A = (const float*)Ap;
            #pragma unroll
            for (int i = 0; i < 4; ++i) {
                int idx = t + i * 256;
                int row = idx >> 3, g = idx & 7;
                float4 v = *reinterpret_cast<const float4*>(A + (size_t)(bm + row) * K + kt * 32 + g * 4);
                alignas(8) f16 hh[4] = {(f16)v.x, (f16)v.y, (f16)v.z, (f16)v.w};
                *reinterpret_cast<uint2*>(&As[row][g * 4]) = *reinterpret_cast<uint2*>(hh);
            }
        }
        #pragma unroll
        for (int i = 0; i < 4; ++i) {
            int idx = t + i * 256;
            int row = idx >> 3, g = idx & 7;
            float4 v = *reinterpret_cast<const float4*>(W + (size_t)(bn + row) * K + kt * 32 + g * 4);
            alignas(8) f16 hh[4] = {(f16)v.x, (f16)v.y, (f16)v.z, (f16)v.w};
            *reinterpret_cast<uint2*>(&Bs[row][g * 4]) = *reinterpret_cast<uint2*>(hh);
        }
        __syncthreads();

        f16x8 af[4], bfv[4];
        #pragma unroll
        for (int m = 0; m < 4; ++m) af[m]  = ldsm8(&As[wr * 64 + m * 16 + lr][lg * 8]);
        #pragma unroll
        for (int n = 0; n < 4; ++n) bfv[n] = ldsm8(&Bs[wc * 64 + n * 16 + lr][lg * 8]);
        #pragma unroll
        for (int m = 0; m < 4; ++m)
            #pragma unroll
            for (int n = 0; n < 4; ++n)
                acc[m][n] = __builtin_amdgcn_mfma_f32_16x16x32_f16(af[m], bfv[n], acc[m][n], 0, 0, 0);
        __syncthreads();
    }

    #pragma unroll
    for (int m = 0; m < 4; ++m) {
        #pragma unroll
        for (int n = 0; n < 4; ++n) {
            int col = bn + wc * 64 + n * 16 + lr;
            float bb = bias[col];
            if (OUT == 2) {
                int row0 = bm + wr * 64 + m * 16 + lg * 4;   // 4 consecutive rows
                int b = row0 >> 11, s = row0 & 2047;
                int hh_ = col >> 6, d = col & 63;
                alignas(8) f16 hv[4];
                #pragma unroll
                for (int j = 0; j < 4; ++j)
                    hv[j] = (f16)((acc[m][n][j] + bb) * scale);
                *reinterpret_cast<uint2*>((f16*)Cp +
                    (((size_t)(b * 16 + hh_) * 64 + d) * 2048 + s)) =
                    *reinterpret_cast<uint2*>(hv);
            } else {
                #pragma unroll
                for (int j = 0; j < 4; ++j) {
                    int row = bm + wr * 64 + m * 16 + lg * 4 + j;
                    float val = (acc[m][n][j] + bb) * scale;
                    if (OUT == 1) ((f16*)Cp)[(size_t)row * N + col] = (f16)val;
                    else          ((float*)Cp)[(size_t)row * N + col] = val;
                }
            }
        }
    }
}

// One block per (b, h, 64-row q-tile). 256 threads = 4 waves:
// wave w: qh_ = w&1 (q half), kh_ = w>>1 (k half of each 64-wide k-tile).
// Swapped QK^T (mfma(K,Q) -> S^T): each lane owns ONE q-row (col = lane&31)
// and 16 k-values (row = (reg&3)+8*(reg>>2)+4*(lane>>5)) -> softmax, the
// normalized fp32 attn store, and PV B-frag packing are all lane-local.
// K and V^T fragments are read DIRECTLY from global (L2-resident via XCD
// swizzle) -- no LDS staging, no per-kt barriers.
__global__ __launch_bounds__(256, 4)
void attn_fused(const f16* __restrict__ qh, const f16* __restrict__ kh,
                const f16* __restrict__ vtg, const int* __restrict__ kmask,
                float* __restrict__ attn_out, f16* __restrict__ ch)
{
    __shared__ float mb[S_];           // mask bias in exp2 domain: 0 or -1e30
    __shared__ float red[2][32];
    __shared__ float linv_s[64];
    __shared__ float cbuf[2][64][32];  // ctx^T cross-wave (kh) reduction

    const int t   = threadIdx.x;
    const int w   = t >> 6, l = t & 63, lo = l & 31, hi = l >> 5;
    const int qh_ = w & 1, kh_ = w >> 1;

    // XCD swizzle: all 32 q-tiles of one (b,h) on one XCD (K/V strip in one L2)
    const int bid  = blockIdx.x;
    const int xcd  = bid & 7;
    const int slot = bid >> 3;
    const int bh   = (xcd << 2) | (slot >> 5);
    const int qt   = slot & 31;
    const int b    = bh >> 4;
    const int h    = bh & 15;
    const int q0   = qt * 64;

    for (int j = t; j < S_; j += 256)
        mb[j] = kmask[b * S_ + j] ? 0.0f : -1e30f;

    // Q B-frags (held in registers for all 32 k-tiles):
    // row q = q0 + qh_*32 + lo, d-chunk c: d = c*16 + hi*8 .. +8
    f16x8 qf[4];
    {
        const f16* qb = qh + (size_t)(b * S_ + q0 + qh_ * 32 + lo) * D_ + h * DH_ + hi * 8;
        #pragma unroll
        for (int c = 0; c < 4; ++c) qf[c] = *reinterpret_cast<const f16x8*>(qb + c * 16);
    }
    __syncthreads();   // mb ready

    const f16* kb = kh  + (size_t)(b * S_ + kh_ * 32 + lo) * D_ + h * DH_ + hi * 8;
    const f16* vb = vtg + ((size_t)(bh * 64 + lo)) * S_ + kh_ * 32 + hi * 8;

    // ---- pass 1: row denominators ----
    float ls = 0.f;
    for (int kt = 0; kt < S_ / 64; ++kt) {
        const f16* kp = kb + (size_t)kt * 64 * D_;
        f16x8 kf[4];
        #pragma unroll
        for (int c = 0; c < 4; ++c) kf[c] = *reinterpret_cast<const f16x8*>(kp + c * 16);
        f32x16 s;
        #pragma unroll
        for (int i = 0; i < 16; ++i) s[i] = 0.f;
        #pragma unroll
        for (int c = 0; c < 4; ++c)
            s = __builtin_amdgcn_mfma_f32_32x32x16_f16(kf[c], qf[c], s, 0, 0, 0);
        #pragma unroll
        for (int q4 = 0; q4 < 4; ++q4) {
            float4 mv = *reinterpret_cast<const float4*>(&mb[kt * 64 + kh_ * 32 + q4 * 8 + hi * 4]);
            ls += __builtin_amdgcn_exp2f(s[q4 * 4 + 0] + mv.x);
            ls += __builtin_amdgcn_exp2f(s[q4 * 4 + 1] + mv.y);
            ls += __builtin_amdgcn_exp2f(s[q4 * 4 + 2] + mv.z);
            ls += __builtin_amdgcn_exp2f(s[q4 * 4 + 3] + mv.w);
        }
    }
    ls += __shfl_xor(ls, 32, 64);
    if (kh_ == 1 && hi == 0) red[qh_][lo] = ls;
    __syncthreads();
    if (kh_ == 0 && hi == 0) linv_s[qh_ * 32 + lo] = 1.0f / (ls + red[qh_][lo]);
    __syncthreads();
    const float invl = linv_s[qh_ * 32 + lo];

    // ---- pass 2: recompute, write normalized attn, accumulate ctx^T ----
    f32x16 oc0, oc1;
    #pragma unroll
    for (int i = 0; i < 16; ++i) { oc0[i] = 0.f; oc1[i] = 0.f; }

    float* ab = attn_out + ((size_t)((b * H_ + h) * S_ + q0 + qh_ * 32 + lo)) * S_
                + kh_ * 32 + hi * 4;

    for (int kt = 0; kt < S_ / 64; ++kt) {
        const f16* kp = kb + (size_t)kt * 64 * D_;
        f16x8 kf[4];
        #pragma unroll
        for (int c = 0; c < 4; ++c) kf[c] = *reinterpret_cast<const f16x8*>(kp + c * 16);
        f32x16 s;
        #pragma unroll
        for (int i = 0; i < 16; ++i) s[i] = 0.f;
        #pragma unroll
        for (int c = 0; c < 4; ++c)
            s = __builtin_amdgcn_mfma_f32_32x32x16_f16(kf[c], qf[c], s, 0, 0, 0);

        float p[16];
        #pragma unroll
        for (int q4 = 0; q4 < 4; ++q4) {
            float4 mv = *reinterpret_cast<const float4*>(&mb[kt * 64 + kh_ * 32 + q4 * 8 + hi * 4]);
            p[q4 * 4 + 0] = __builtin_amdgcn_exp2f(s[q4 * 4 + 0] + mv.x) * invl;
            p[q4 * 4 + 1] = __builtin_amdgcn_exp2f(s[q4 * 4 + 1] + mv.y) * invl;
            p[q4 * 4 + 2] = __builtin_amdgcn_exp2f(s[q4 * 4 + 2] + mv.z) * invl;
            p[q4 * 4 + 3] = __builtin_amdgcn_exp2f(s[q4 * 4 + 3] + mv.w) * invl;
        }

        // normalized attn store: reg-quad q4 -> k = kt*64 + kh_*32 + 8*q4 + 4*hi + j
        #pragma unroll
        for (int q4 = 0; q4 < 4; ++q4) {
            float4 o = {p[q4 * 4 + 0], p[q4 * 4 + 1], p[q4 * 4 + 2], p[q4 * 4 + 3]};
            *reinterpret_cast<float4*>(ab + (size_t)kt * 64 + q4 * 8) = o;
        }

        // PV: B-frag from in-register P via pack + half-wave exchange
        #pragma unroll
        for (int j2 = 0; j2 < 2; ++j2) {
            unsigned wds[4], ods[4];
            #pragma unroll
            for (int i = 0; i < 4; ++i) {
                f16x2 pr = {(f16)p[8 * j2 + 2 * i], (f16)p[8 * j2 + 2 * i + 1]};
                wds[i] = __builtin_bit_cast(unsigned, pr);
            }
            #pragma unroll
            for (int i = 0; i < 4; ++i)
                ods[i] = (unsigned)__shfl_xor((int)wds[i], 32, 64);
            uint4 bw = (hi == 0) ? (uint4){wds[0], wds[1], ods[0], ods[1]}
                                 : (uint4){ods[2], ods[3], wds[2], wds[3]};
            f16x8 bf = __builtin_bit_cast(f16x8, bw);

            const f16* vp = vb + (size_t)kt * 64 + j2 * 16;
            f16x8 va0 = *reinterpret_cast<const f16x8*>(vp);
            f16x8 va1 = *reinterpret_cast<const f16x8*>(vp + (size_t)32 * S_);
            oc0 = __builtin_amdgcn_mfma_f32_32x32x16_f16(va0, bf, oc0, 0, 0, 0);
            oc1 = __builtin_amdgcn_mfma_f32_32x32x16_f16(va1, bf, oc1, 0, 0, 0);
        }
    }

    // ---- cross-wave (kh) ctx reduction + store ----
    if (kh_ == 1) {
        #pragma unroll
        for (int r = 0; r < 16; ++r) {
            int d0 = (r & 3) + 8 * (r >> 2) + 4 * hi;
            cbuf[qh_][d0][lo]      = oc0[r];
            cbuf[qh_][32 + d0][lo] = oc1[r];
        }
    }
    __syncthreads();
    if (kh_ == 0) {
        #pragma unroll
        for (int r = 0; r < 16; ++r) {
            int d0 = (r & 3) + 8 * (r >> 2) + 4 * hi;
            oc0[r] += cbuf[qh_][d0][lo];
            oc1[r] += cbuf[qh_][32 + d0][lo];
        }
        f16* cb = ch + (size_t)(b * S_ + q0 + qh_ * 32 + lo) * D_ + h * DH_;
        #pragma unroll
        for (int q4 = 0; q4 < 4; ++q4) {
            int d0 = 8 * q4 + 4 * hi;
            f16x4 v0 = {(f16)oc0[4 * q4 + 0], (f16)oc0[4 * q4 + 1],
                        (f16)oc0[4 * q4 + 2], (f16)oc0[4 * q4 + 3]};
            *reinterpret_cast<f16x4*>(cb + d0) = v0;
            f16x4 v1 = {(f16)oc1[4 * q4 + 0], (f16)oc1[4 * q4 + 1],
                        (f16)oc1[4 * q4 + 2], (f16)oc1[4 * q4 + 3]};
            *reinterpret_cast<f16x4*>(cb + 32 + d0) = v1;
        }
    }
}

extern "C" void kernel_launch(void* const* d_in, const int* in_sizes, int n_in,
                              void* d_out, int out_size, void* d_ws, size_t ws_size,
                              hipStream_t stream) {
    const float* query = (const float*)d_in[0];
    const float* key   = (const float*)d_in[1];
    const float* value = (const float*)d_in[2];
    const int*   kmask = (const int*)d_in[3];
    const float* Wq = (const float*)d_in[4];
    const float* bq = (const float*)d_in[5];
    const float* Wk = (const float*)d_in[6];
    const float* bk = (const float*)d_in[7];
    const float* Wv = (const float*)d_in[8];
    const float* bv = (const float*)d_in[9];
    const float* Wo = (const float*)d_in[10];
    const float* bo = (const float*)d_in[11];

    float* out  = (float*)d_out;
    float* attn = out + (size_t)B_ * S_ * D_;

    const size_t NE = (size_t)B_ * S_ * D_;
    f16* qhp = (f16*)d_ws;
    f16* khp = qhp + NE;
    f16* vtg = khp + NE;         // per-head transposed V: [(b*16+h)*64+d][s]
    f16* chx = vtg + NE;         // 32 MB of ws total

    dim3 grid(8, 32), blk(256);
    const float qscale = 0.125f * 1.44269504088896340736f;   // (1/sqrt(DH)) * log2(e)

    gemm_bt<0, 1><<<grid, blk, 0, stream>>>((const void*)query, Wq, bq, (void*)qhp, qscale);
    gemm_bt<0, 1><<<grid, blk, 0, stream>>>((const void*)key,   Wk, bk, (void*)khp, 1.0f);
    gemm_bt<0, 2><<<grid, blk, 0, stream>>>((const void*)value, Wv, bv, (void*)vtg, 1.0f);

    attn_fused<<<dim3(B_ * H_ * (S_ / 64)), blk, 0, stream>>>(qhp, khp, vtg, kmask, attn, chx);

    gemm_bt<1, 0><<<grid, blk, 0, stream>>>((const void*)chx, Wo, bo, (void*)out, 1.0f);
}